// Round 1
// baseline (143.197 us; speedup 1.0000x reference)
//
#include <hip/hip_runtime.h>
#include <math.h>
#include <stdint.h>

// Problem constants (from reference): B,K,V,T,S,H = 128,10,50257,20,4,2048; t read from input.
#define NB 128
#define NK 10
#define NV 50257
#define NT 20
#define NS 4
#define NH 2048

// ---------------------------------------------------------------------------
// Kernel 1: per-(b,k) row top-10 of logprobs (with -1000 penalty on V-1).
// One 256-thread block per row. Per-thread register top-10 (stable, earliest
// index wins ties), then LDS tree-merge of sorted 10-lists.
// ---------------------------------------------------------------------------
__global__ __launch_bounds__(256) void topk_rows(const float* __restrict__ lp,
                                                 float* __restrict__ ys,   // (B*K, 10)
                                                 int*   __restrict__ ix) { // (B*K, 10)
    const int row = blockIdx.x;      // 0 .. B*K-1
    const int tid = threadIdx.x;
    const float* rowp = lp + (size_t)row * NV;

    float vals[10];
    int   idxs[10];
#pragma unroll
    for (int j = 0; j < 10; ++j) { vals[j] = -INFINITY; idxs[j] = 0x7fffffff; }

    auto consider = [&](float v, int idx) {
        if (v > vals[9]) {
            vals[9] = v; idxs[9] = idx;
#pragma unroll
            for (int j = 9; j >= 1; --j) {
                if (vals[j] > vals[j - 1]) {   // strict > keeps stability for ties
                    float tv = vals[j]; vals[j] = vals[j - 1]; vals[j - 1] = tv;
                    int   ti = idxs[j]; idxs[j] = idxs[j - 1]; idxs[j - 1] = ti;
                }
            }
        }
    };

    // Align to 16B for float4 main loop (row stride 50257 floats is odd).
    int head = (int)(((16u - (unsigned)((uintptr_t)rowp & 15u)) & 15u) >> 2);
    if (tid < head) {
        int idx = tid;
        float v = rowp[idx];
        if (idx == NV - 1) v -= 1000.0f;
        consider(v, idx);
    }
    const int n4 = (NV - head) >> 2;
    const float4* rowp4 = (const float4*)(rowp + head);
    for (int j = tid; j < n4; j += 256) {
        float4 v4 = rowp4[j];
        int base = head + 4 * j;
        float a0 = v4.x, a1 = v4.y, a2 = v4.z, a3 = v4.w;
        if (base + 0 == NV - 1) a0 -= 1000.0f;
        if (base + 1 == NV - 1) a1 -= 1000.0f;
        if (base + 2 == NV - 1) a2 -= 1000.0f;
        if (base + 3 == NV - 1) a3 -= 1000.0f;
        consider(a0, base + 0);
        consider(a1, base + 1);
        consider(a2, base + 2);
        consider(a3, base + 3);
    }
    const int tail = head + n4 * 4;
    for (int idx = tail + tid; idx < NV; idx += 256) {
        float v = rowp[idx];
        if (idx == NV - 1) v -= 1000.0f;
        consider(v, idx);
    }

    // LDS tree-merge: 256 sorted 10-lists -> 1 sorted 10-list.
    __shared__ float sv[256 * 10];
    __shared__ int   si[256 * 10];
#pragma unroll
    for (int j = 0; j < 10; ++j) { sv[tid * 10 + j] = vals[j]; si[tid * 10 + j] = idxs[j]; }

    for (int s = 128; s >= 1; s >>= 1) {
        __syncthreads();
        float mv[10]; int mi[10];
        if (tid < s) {
            int ia = 0, ib = 0;
            const int ba = tid * 10, bb = (tid + s) * 10;
#pragma unroll
            for (int r = 0; r < 10; ++r) {
                float va = sv[ba + ia], vb = sv[bb + ib];
                int   xa = si[ba + ia], xb = si[bb + ib];
                bool ta = (va > vb) || (va == vb && xa < xb);  // stable: smaller idx first
                mv[r] = ta ? va : vb;
                mi[r] = ta ? xa : xb;
                ia += ta ? 1 : 0;
                ib += ta ? 0 : 1;
            }
        }
        __syncthreads();
        if (tid < s) {
#pragma unroll
            for (int r = 0; r < 10; ++r) { sv[tid * 10 + r] = mv[r]; si[tid * 10 + r] = mi[r]; }
        }
    }
    __syncthreads();
    if (tid < 10) {
        ys[row * 10 + tid] = sv[tid];
        ix[row * 10 + tid] = si[tid];
    }
}

// ---------------------------------------------------------------------------
// Kernel 2: per-batch candidate selection + seq/seq_lp/p outputs.
// flat[c*K+q] = lp_sum[q] + ys[q][c]; top-10 with argsort-stable tie-break.
// ---------------------------------------------------------------------------
__global__ __launch_bounds__(128) void beam_select(
    const float* __restrict__ lp_sum,   // (B,K)
    const float* __restrict__ seq_lp,   // (B,T,K)
    const int*   __restrict__ seq,      // (B,T,K) int32
    const int*   __restrict__ tptr,     // scalar t
    const float* __restrict__ ys,       // (B*K,10)
    const int*   __restrict__ ix,       // (B*K,10)
    float* __restrict__ out_seq,        // (B,T,K) as float
    float* __restrict__ out_seq_lp,     // (B,T,K)
    float* __restrict__ out_p,          // (B,K)
    int*   __restrict__ qsel_out)       // (B,K) scratch for kernel 3
{
    const int b = blockIdx.x;
    const int tid = threadIdx.x;
    const int t = tptr[0];

    __shared__ float sf[100];
    __shared__ int   so[10];
    __shared__ int   sq[10];
    __shared__ int   stok[10];
    __shared__ float sr[10];

    if (tid < 100) {
        int c = tid / 10, q = tid % 10;  // flat index f = c*K + q
        sf[tid] = lp_sum[b * 10 + q] + ys[(b * 10 + q) * 10 + c];
    }
    __syncthreads();
    if (tid < 100) {
        float v = sf[tid];
        int rank = 0;
        for (int j = 0; j < 100; ++j) {
            float u = sf[j];
            rank += (u > v || (u == v && j < tid)) ? 1 : 0;
        }
        if (rank < 10) so[rank] = tid;
    }
    __syncthreads();
    if (tid < 10) {
        int f = so[tid];
        int c = f / 10, q = f % 10;
        sq[tid] = q;
        stok[tid] = ix[(b * 10 + q) * 10 + c];
        sr[tid] = ys[(b * 10 + q) * 10 + c];
        out_p[b * 10 + tid] = sf[f];
        qsel_out[b * 10 + tid] = q;
    }
    __syncthreads();
    for (int i = tid; i < NT * 10; i += 128) {
        int time = i / 10, k = i % 10;
        int qs = sq[k];
        int src_k = (time < t) ? qs : k;
        int   sval = seq[(b * NT + time) * 10 + src_k];
        float lv = seq_lp[(b * NT + time) * 10 + src_k];
        if (time == t) { sval = stok[k]; lv = sr[k]; }
        out_seq[(b * NT + time) * 10 + k]    = (float)sval;   // exact: tokens < 2^24
        out_seq_lp[(b * NT + time) * 10 + k] = lv;
    }
}

// ---------------------------------------------------------------------------
// Kernel 3: new_state[b,s,k,:] = state[b,s,q_sel[b,k],:]  (8KB rows, float4)
// ---------------------------------------------------------------------------
__global__ __launch_bounds__(256) void state_gather(
    const float* __restrict__ st,     // (B,S,K,H)
    const int*   __restrict__ qsel,   // (B,K)
    float* __restrict__ out_st)       // (B,S,K,H)
{
    const int row = blockIdx.x;       // b*S*K + s*K + k   (5120 rows)
    const int k  = row % NK;
    const int bs = row / NK;          // b*S + s
    const int b  = bs / NS;
    const int q  = qsel[b * NK + k];

    const float4* src = (const float4*)(st + ((size_t)bs * NK + q) * NH);
    float4*       dst = (float4*)(out_st + (size_t)row * NH);
    const int tid = threadIdx.x;
    dst[tid]       = src[tid];
    dst[tid + 256] = src[tid + 256];
}

extern "C" void kernel_launch(void* const* d_in, const int* in_sizes, int n_in,
                              void* d_out, int out_size, void* d_ws, size_t ws_size,
                              hipStream_t stream) {
    const float* lp      = (const float*)d_in[0];  // (B,K,V)
    const float* lp_sum  = (const float*)d_in[1];  // (B,K)
    const float* seq_lp  = (const float*)d_in[2];  // (B,T,K)
    const float* st      = (const float*)d_in[3];  // (B,S,K,H)
    const int*   seq     = (const int*)d_in[4];    // (B,T,K)
    const int*   tptr    = (const int*)d_in[5];    // scalar t

    float* out        = (float*)d_out;
    float* out_seq    = out;                         // 25600
    float* out_seq_lp = out + NB * NT * NK;          // +25600
    float* out_p      = out + 2 * NB * NT * NK;      // +1280
    float* out_st     = out + 2 * NB * NT * NK + NB * NK;

    float* ws_ys   = (float*)d_ws;                            // 12800 floats
    int*   ws_ix   = (int*)((char*)d_ws + 51200);             // 12800 ints
    int*   ws_qsel = (int*)((char*)d_ws + 102400);            // 1280 ints

    topk_rows<<<NB * NK, 256, 0, stream>>>(lp, ws_ys, ws_ix);
    beam_select<<<NB, 128, 0, stream>>>(lp_sum, seq_lp, seq, tptr, ws_ys, ws_ix,
                                        out_seq, out_seq_lp, out_p, ws_qsel);
    state_gather<<<NB * NS * NK, 256, 0, stream>>>(st, ws_qsel, out_st);
}

// Round 2
// 115.218 us; speedup vs baseline: 1.2428x; 1.2428x over previous
//
#include <hip/hip_runtime.h>
#include <math.h>
#include <stdint.h>

// B,K,V,T,S,H = 128,10,50257,20,4,2048; t read from input.
#define NB 128
#define NK 10
#define NV 50257
#define NT 20
#define NS 4
#define NH 2048

// Monotone bijection float -> uint32 (no NaNs in data): preserves order.
__device__ __forceinline__ unsigned key_of(float f) {
    unsigned u = __float_as_uint(f);
    unsigned m = (unsigned)((int)u >> 31) | 0x80000000u; // neg: ~0, pos: sign bit
    return u ^ m;
}
__device__ __forceinline__ float val_of(unsigned k) {
    unsigned m = (k & 0x80000000u) ? 0x80000000u : 0xFFFFFFFFu;
    return __uint_as_float(k ^ m);
}

// Sorted-descending 10-list of u64 keys; static indices only (no scratch).
__device__ __forceinline__ void insert10(unsigned long long (&L)[10], unsigned long long c) {
    L[9] = c;
#pragma unroll
    for (int j = 9; j >= 1; --j) {
        unsigned long long a = L[j - 1], b = L[j];
        bool sw = b > a;
        L[j - 1] = sw ? b : a;
        L[j]     = sw ? a : b;
    }
}

// ---------------------------------------------------------------------------
// Kernel 1: per-(b,k) row top-10. 256 threads/row; each wave keeps ONE
// wave-uniform top-10 (packed u64: key32<<32 | ~idx => total order =
// (val desc, idx asc), matching jax.lax.top_k tie-breaks). Common path per
// element: 1 cmp + ballot; rare path (~81/row/wave): shfl + bubble insert.
// ---------------------------------------------------------------------------
__global__ __launch_bounds__(256) void topk_rows(const float* __restrict__ lp,
                                                 float* __restrict__ ys,   // (B*K,10)
                                                 int*   __restrict__ ix) { // (B*K,10)
    const int row = blockIdx.x;
    const int tid = threadIdx.x;
    const float* rowp = lp + (size_t)row * NV;

    unsigned long long L[10];
#pragma unroll
    for (int j = 0; j < 10; ++j) L[j] = 0ull; // real keys always > 0

    auto process = [&](unsigned k, bool valid, int idx) {
        unsigned thr = (unsigned)(L[9] >> 32);
        unsigned long long m = __ballot(valid && k >= thr);
        while (m) {
            int l = __ffsll(m) - 1;
            m &= m - 1;
            unsigned ck = __shfl(k, l);
            int      ci = __shfl(idx, l);
            unsigned long long cand =
                ((unsigned long long)ck << 32) | (unsigned)(~(unsigned)ci);
            if (cand > L[9]) insert10(L, cand);
        }
    };

    // Align to 16B (row stride 50257 floats is odd -> head in {0,1,2,3}).
    const int head = (int)(((16u - (unsigned)((uintptr_t)rowp & 15u)) & 15u) >> 2);
    {   // prologue: [0, head)
        bool valid = tid < head;
        float v = valid ? rowp[tid] : 0.0f;
        process(key_of(v), valid, tid);
    }
    // main: [head, head+4*n4) over NV-1 elements (last elem handled in epilogue)
    const int n4 = (NV - 1 - head) >> 2;
    const float4* rowp4 = (const float4*)(rowp + head);
    for (int j = tid; j < n4; j += 256) {
        float4 v4 = rowp4[j];
        int base = head + 4 * j;
        process(key_of(v4.x), true, base + 0);
        process(key_of(v4.y), true, base + 1);
        process(key_of(v4.z), true, base + 2);
        process(key_of(v4.w), true, base + 3);
    }
    {   // epilogue: [head+4*n4, NV-1] incl. penalized last element
        int idx = head + 4 * n4 + tid;
        bool valid = idx < NV;
        float v = valid ? rowp[idx] : 0.0f;
        if (idx == NV - 1) v -= 1000.0f;
        process(key_of(v), valid, idx);
    }

    // Merge 4 wave-lists (40 distinct u64s) by rank-counting.
    __shared__ unsigned long long sm[40];
    if ((tid & 63) == 0) {
        const int w = tid >> 6;
#pragma unroll
        for (int r = 0; r < 10; ++r) sm[w * 10 + r] = L[r];
    }
    __syncthreads();
    if (tid < 40) {
        unsigned long long my = sm[tid];
        int rank = 0;
#pragma unroll
        for (int j = 0; j < 40; ++j) rank += (sm[j] > my) ? 1 : 0;
        if (rank < 10) {
            unsigned k32 = (unsigned)(my >> 32);
            int idx = (int)(~(unsigned)(my & 0xFFFFFFFFull));
            ys[row * 10 + rank] = val_of(k32);
            ix[row * 10 + rank] = idx;
        }
    }
}

// ---------------------------------------------------------------------------
// Kernel 2: per-batch candidate selection + seq/seq_lp/p outputs.
// ---------------------------------------------------------------------------
__global__ __launch_bounds__(128) void beam_select(
    const float* __restrict__ lp_sum,   // (B,K)
    const float* __restrict__ seq_lp,   // (B,T,K)
    const int*   __restrict__ seq,      // (B,T,K) int32
    const int*   __restrict__ tptr,     // scalar t
    const float* __restrict__ ys,       // (B*K,10)
    const int*   __restrict__ ix,       // (B*K,10)
    float* __restrict__ out_seq,        // (B,T,K) as float
    float* __restrict__ out_seq_lp,     // (B,T,K)
    float* __restrict__ out_p,          // (B,K)
    int*   __restrict__ qsel_out)       // (B,K) scratch for kernel 3
{
    const int b = blockIdx.x;
    const int tid = threadIdx.x;
    const int t = tptr[0];

    __shared__ float sf[100];
    __shared__ int   so[10];
    __shared__ int   sq[10];
    __shared__ int   stok[10];
    __shared__ float sr[10];

    if (tid < 100) {
        int c = tid / 10, q = tid % 10;  // flat f = c*K + q
        sf[tid] = lp_sum[b * 10 + q] + ys[(b * 10 + q) * 10 + c];
    }
    __syncthreads();
    if (tid < 100) {
        float v = sf[tid];
        int rank = 0;
        for (int j = 0; j < 100; ++j) {
            float u = sf[j];
            rank += (u > v || (u == v && j < tid)) ? 1 : 0; // argsort-stable
        }
        if (rank < 10) so[rank] = tid;
    }
    __syncthreads();
    if (tid < 10) {
        int f = so[tid];
        int c = f / 10, q = f % 10;
        sq[tid] = q;
        stok[tid] = ix[(b * 10 + q) * 10 + c];
        sr[tid] = ys[(b * 10 + q) * 10 + c];
        out_p[b * 10 + tid] = sf[f];
        qsel_out[b * 10 + tid] = q;
    }
    __syncthreads();
    for (int i = tid; i < NT * 10; i += 128) {
        int time = i / 10, k = i % 10;
        int qs = sq[k];
        int src_k = (time < t) ? qs : k;
        int   sval = seq[(b * NT + time) * 10 + src_k];
        float lv = seq_lp[(b * NT + time) * 10 + src_k];
        if (time == t) { sval = stok[k]; lv = sr[k]; }
        out_seq[(b * NT + time) * 10 + k]    = (float)sval; // exact: tokens < 2^24
        out_seq_lp[(b * NT + time) * 10 + k] = lv;
    }
}

// ---------------------------------------------------------------------------
// Kernel 3: new_state[b,s,k,:] = state[b,s,q_sel[b,k],:]  (8KB rows, float4)
// ---------------------------------------------------------------------------
__global__ __launch_bounds__(256) void state_gather(
    const float* __restrict__ st,     // (B,S,K,H)
    const int*   __restrict__ qsel,   // (B,K)
    float* __restrict__ out_st)       // (B,S,K,H)
{
    const int row = blockIdx.x;       // b*S*K + s*K + k
    const int k  = row % NK;
    const int bs = row / NK;          // b*S + s
    const int b  = bs / NS;
    const int q  = qsel[b * NK + k];

    const float4* src = (const float4*)(st + ((size_t)bs * NK + q) * NH);
    float4*       dst = (float4*)(out_st + (size_t)row * NH);
    const int tid = threadIdx.x;
    dst[tid]       = src[tid];
    dst[tid + 256] = src[tid + 256];
}

extern "C" void kernel_launch(void* const* d_in, const int* in_sizes, int n_in,
                              void* d_out, int out_size, void* d_ws, size_t ws_size,
                              hipStream_t stream) {
    const float* lp      = (const float*)d_in[0];  // (B,K,V)
    const float* lp_sum  = (const float*)d_in[1];  // (B,K)
    const float* seq_lp  = (const float*)d_in[2];  // (B,T,K)
    const float* st      = (const float*)d_in[3];  // (B,S,K,H)
    const int*   seq     = (const int*)d_in[4];    // (B,T,K)
    const int*   tptr    = (const int*)d_in[5];    // scalar t

    float* out        = (float*)d_out;
    float* out_seq    = out;                         // 25600
    float* out_seq_lp = out + NB * NT * NK;          // +25600
    float* out_p      = out + 2 * NB * NT * NK;      // +1280
    float* out_st     = out + 2 * NB * NT * NK + NB * NK;

    float* ws_ys   = (float*)d_ws;                   // 12800 floats
    int*   ws_ix   = (int*)((char*)d_ws + 51200);    // 12800 ints
    int*   ws_qsel = (int*)((char*)d_ws + 102400);   // 1280 ints

    topk_rows<<<NB * NK, 256, 0, stream>>>(lp, ws_ys, ws_ix);
    beam_select<<<NB, 128, 0, stream>>>(lp_sum, seq_lp, seq, tptr, ws_ys, ws_ix,
                                        out_seq, out_seq_lp, out_p, ws_qsel);
    state_gather<<<NB * NS * NK, 256, 0, stream>>>(st, ws_qsel, out_st);
}